// Round 1
// baseline (119.092 us; speedup 1.0000x reference)
//
#include <hip/hip_runtime.h>

// Problem constants (match reference)
constexpr int B = 128;
constexpr int N = 262144;
constexpr int CHUNKS = 16;                 // blocks per sample
constexpr int THREADS = 256;
constexpr int V4_PER_SAMPLE = N / 4;       // 65536 float4 per class-row
constexpr int V4_PER_CHUNK = V4_PER_SAMPLE / CHUNKS;   // 4096
constexpr int ITERS = V4_PER_CHUNK / THREADS;          // 16

__device__ __forceinline__ void elem(float x0, float x1, int lv, float w,
                                     float& sum, float& npos) {
    float d  = x0 - x1;
    float ad = fabsf(d);
    float t  = log1pf(__expf(-ad));        // shared softplus tail
    // negative: softplus(x1-x0) = max(-d,0)+t ; positive: w*(max(d,0)+t)
    float neg = fmaxf(-d, 0.f) + t;
    float pos = fmaxf( d, 0.f) + t;
    bool isPos = (lv == 1);
    sum  += isPos ? (w * pos) : neg;
    npos += isPos ? 1.f : 0.f;
}

__global__ __launch_bounds__(THREADS) void ce_partial(
    const float* __restrict__ inp, const int* __restrict__ label,
    const float* __restrict__ weightp,
    float* __restrict__ ws_per, float* __restrict__ ws_npos) {
    const int b = blockIdx.y;
    const int chunk = blockIdx.x;
    const float w = weightp[0];

    const float4* p0  = reinterpret_cast<const float4*>(inp + (size_t)b * 2 * N);
    const float4* p1  = reinterpret_cast<const float4*>(inp + (size_t)b * 2 * N + N);
    const int4*   lab = reinterpret_cast<const int4*>(label + (size_t)b * N);

    float sum = 0.f, npos = 0.f;
    int base = chunk * V4_PER_CHUNK + threadIdx.x;
    #pragma unroll 4
    for (int i = 0; i < ITERS; ++i) {
        int idx = base + i * THREADS;
        float4 a = p0[idx];
        float4 c = p1[idx];
        int4   l = lab[idx];
        elem(a.x, c.x, l.x, w, sum, npos);
        elem(a.y, c.y, l.y, w, sum, npos);
        elem(a.z, c.z, l.z, w, sum, npos);
        elem(a.w, c.w, l.w, w, sum, npos);
    }

    // wave reduce (64 lanes)
    for (int o = 32; o > 0; o >>= 1) {
        sum  += __shfl_down(sum, o);
        npos += __shfl_down(npos, o);
    }
    __shared__ float red_s[THREADS / 64];
    __shared__ float red_n[THREADS / 64];
    int lane = threadIdx.x & 63;
    int wid  = threadIdx.x >> 6;
    if (lane == 0) { red_s[wid] = sum; red_n[wid] = npos; }
    __syncthreads();
    if (threadIdx.x == 0) {
        float s = 0.f, n = 0.f;
        #pragma unroll
        for (int i = 0; i < THREADS / 64; ++i) { s += red_s[i]; n += red_n[i]; }
        int slot = b * CHUNKS + chunk;
        ws_per[slot]  = s;
        ws_npos[slot] = n;
    }
}

__global__ __launch_bounds__(128) void ce_final(
    const float* __restrict__ ws_per, const float* __restrict__ ws_npos,
    const float* __restrict__ weightp, float* __restrict__ out) {
    const float w = weightp[0];
    int b = threadIdx.x;   // 128 threads, one per sample
    float sp = 0.f, np = 0.f;
    #pragma unroll
    for (int c = 0; c < CHUNKS; ++c) {
        sp += ws_per[b * CHUNKS + c];
        np += ws_npos[b * CHUNKS + c];
    }
    float ps = sp / ((float)N + (w - 1.f) * np);
    // reduce 128 threads = 2 waves
    for (int o = 32; o > 0; o >>= 1) ps += __shfl_down(ps, o);
    __shared__ float red[2];
    if ((threadIdx.x & 63) == 0) red[threadIdx.x >> 6] = ps;
    __syncthreads();
    if (threadIdx.x == 0) out[0] = (red[0] + red[1]) / (float)B;
}

extern "C" void kernel_launch(void* const* d_in, const int* in_sizes, int n_in,
                              void* d_out, int out_size, void* d_ws, size_t ws_size,
                              hipStream_t stream) {
    const float* inp     = (const float*)d_in[0];
    const int*   label   = (const int*)d_in[1];
    const float* weightp = (const float*)d_in[2];
    float* out = (float*)d_out;

    float* ws_per  = (float*)d_ws;
    float* ws_npos = ws_per + B * CHUNKS;

    dim3 grid(CHUNKS, B);
    ce_partial<<<grid, THREADS, 0, stream>>>(inp, label, weightp, ws_per, ws_npos);
    ce_final<<<1, 128, 0, stream>>>(ws_per, ws_npos, weightp, out);
}

// Round 2
// 75.512 us; speedup vs baseline: 1.5771x; 1.5771x over previous
//
#include <hip/hip_runtime.h>

// Problem constants (match reference)
constexpr int B = 128;
constexpr int N = 262144;
constexpr int CHUNKS = 16;                 // blocks per sample
constexpr int THREADS = 256;
constexpr int V4_PER_SAMPLE = N / 4;       // 65536 float4 per class-row
constexpr int V4_PER_CHUNK = V4_PER_SAMPLE / CHUNKS;   // 4096
constexpr int ITERS = V4_PER_CHUNK / THREADS;          // 16

__device__ __forceinline__ void elem(float x0, float x1, int lv, float w,
                                     float& sum, int& npos) {
    float d  = x0 - x1;                    // p0 - p1
    float ad = fabsf(d);
    // softplus tail shared by both branches; HW trans only:
    // t = log(1 + exp(-|d|)) via v_exp_f32 + v_log_f32
    float t  = __logf(1.0f + __expf(-ad));
    bool isPos = (lv != 0);
    float sd   = isPos ? d : -d;           // v_cndmask (with -d via xor/mod)
    float coef = isPos ? w : 1.0f;         // v_cndmask
    sum  = fmaf(coef, fmaxf(sd, 0.0f) + t, sum);
    npos += lv;                            // labels are exactly 0/1
}

__global__ __launch_bounds__(THREADS) void ce_partial(
    const float* __restrict__ inp, const int* __restrict__ label,
    const float* __restrict__ weightp,
    float* __restrict__ ws_per, float* __restrict__ ws_npos) {
    const int b = blockIdx.y;
    const int chunk = blockIdx.x;
    const float w = weightp[0];

    const float4* p0  = reinterpret_cast<const float4*>(inp + (size_t)b * 2 * N);
    const float4* p1  = reinterpret_cast<const float4*>(inp + (size_t)b * 2 * N + N);
    const int4*   lab = reinterpret_cast<const int4*>(label + (size_t)b * N);

    float sum = 0.f;
    int   npos = 0;
    int base = chunk * V4_PER_CHUNK + threadIdx.x;
    #pragma unroll 4
    for (int i = 0; i < ITERS; ++i) {
        int idx = base + i * THREADS;
        float4 a = p0[idx];
        float4 c = p1[idx];
        int4   l = lab[idx];
        elem(a.x, c.x, l.x, w, sum, npos);
        elem(a.y, c.y, l.y, w, sum, npos);
        elem(a.z, c.z, l.z, w, sum, npos);
        elem(a.w, c.w, l.w, w, sum, npos);
    }

    float nposf = (float)npos;
    // wave reduce (64 lanes)
    for (int o = 32; o > 0; o >>= 1) {
        sum   += __shfl_down(sum, o);
        nposf += __shfl_down(nposf, o);
    }
    __shared__ float red_s[THREADS / 64];
    __shared__ float red_n[THREADS / 64];
    int lane = threadIdx.x & 63;
    int wid  = threadIdx.x >> 6;
    if (lane == 0) { red_s[wid] = sum; red_n[wid] = nposf; }
    __syncthreads();
    if (threadIdx.x == 0) {
        float s = 0.f, n = 0.f;
        #pragma unroll
        for (int i = 0; i < THREADS / 64; ++i) { s += red_s[i]; n += red_n[i]; }
        int slot = b * CHUNKS + chunk;
        ws_per[slot]  = s;
        ws_npos[slot] = n;
    }
}

__global__ __launch_bounds__(128) void ce_final(
    const float* __restrict__ ws_per, const float* __restrict__ ws_npos,
    const float* __restrict__ weightp, float* __restrict__ out) {
    const float w = weightp[0];
    int b = threadIdx.x;   // 128 threads, one per sample
    float sp = 0.f, np = 0.f;
    #pragma unroll
    for (int c = 0; c < CHUNKS; ++c) {
        sp += ws_per[b * CHUNKS + c];
        np += ws_npos[b * CHUNKS + c];
    }
    float ps = sp / ((float)N + (w - 1.f) * np);
    // reduce 128 threads = 2 waves
    for (int o = 32; o > 0; o >>= 1) ps += __shfl_down(ps, o);
    __shared__ float red[2];
    if ((threadIdx.x & 63) == 0) red[threadIdx.x >> 6] = ps;
    __syncthreads();
    if (threadIdx.x == 0) out[0] = (red[0] + red[1]) / (float)B;
}

extern "C" void kernel_launch(void* const* d_in, const int* in_sizes, int n_in,
                              void* d_out, int out_size, void* d_ws, size_t ws_size,
                              hipStream_t stream) {
    const float* inp     = (const float*)d_in[0];
    const int*   label   = (const int*)d_in[1];
    const float* weightp = (const float*)d_in[2];
    float* out = (float*)d_out;

    float* ws_per  = (float*)d_ws;
    float* ws_npos = ws_per + B * CHUNKS;

    dim3 grid(CHUNKS, B);
    ce_partial<<<grid, THREADS, 0, stream>>>(inp, label, weightp, ws_per, ws_npos);
    ce_final<<<1, 128, 0, stream>>>(ws_per, ws_npos, weightp, out);
}